// Round 2
// baseline (495.352 us; speedup 1.0000x reference)
//
#include <hip/hip_runtime.h>

#define SIDE 9
#define STATE 81
#define NA 5
#define NJ (STATE * NA)   // 405
#define H1 32
#define H2 32

#define CCH 27            // chunk columns (405 = 15*27, 81 = 3*27)
#define ROWS 64           // rows per 64-thread block (1 wave)
#define NAF 15            // af chunks
#define NCH 18            // 15 af + 3 demand

// Compile-time inflow destination table: j = s*NA + a  ->  dest state.
struct DstTab { int v[NJ]; };
constexpr DstTab make_dst() {
    DstTab t{};
    const int dr[NA] = {0, -1, 1, 0, 0};
    const int dc[NA] = {0, 0, 0, -1, 1};
    for (int s = 0; s < STATE; ++s) {
        int r = s / SIDE, c = s % SIDE;
        for (int a = 0; a < NA; ++a) {
            int nr = r + dr[a], nc = c + dc[a];
            int d = (nr >= 0 && nr < SIDE && nc >= 0 && nc < SIDE) ? nr * SIDE + nc : s;
            t.v[s * NA + a] = d;
        }
    }
    return t;
}
constexpr DstTab DST = make_dst();

typedef const float __attribute__((address_space(1)))* gas_fptr;
typedef float __attribute__((address_space(3)))* las_fptr;

__global__ __launch_bounds__(64, 2) void grid_vpn_kernel(
    const float* __restrict__ obs,        // (B, 243)
    const float* __restrict__ af,         // (B, 405)
    const float* __restrict__ W1,         // (81, 32)
    const float* __restrict__ W2,         // (32, 32)
    const float* __restrict__ W3,         // (32, 1)
    const float* __restrict__ b3,         // (1,)
    float* __restrict__ out,              // [sym(B) | ir(B) | nr(B) | nsc(B*81)]
    int B)
{
    __shared__ float buf[2][ROWS * CCH];  // 2 x 6.75 KB double buffer
    const int lane = (int)threadIdx.x;    // 0..63, thread == row within tile
    const int r0   = (int)blockIdx.x * ROWS;
    const int Bm1  = B - 1;

    // per-lane start of the e = t*64 + lane -> (row, col) decomposition (e/27, e%27)
    const int lr0 = lane / CCH;
    const int lc0 = lane - lr0 * CCH;

    // Stage one 64-row x 27-col chunk into LDS buffer (c&1).
    // LDS dest is linear in lane (HW requirement for global_load_lds);
    // flat LDS word e = t*64+lane == row*27+col of the tile -> [row][27] layout.
    auto issue = [&](int c) {
        const float* src = (c < NAF) ? af : obs;
        const int stride = (c < NAF) ? NJ : 3 * STATE;
        const int cb     = (c < NAF) ? c * CCH : 2 * STATE + (c - NAF) * CCH;
        float* lb = &buf[c & 1][0];
        int r = lr0, col = lc0;
#pragma unroll
        for (int t = 0; t < CCH; ++t) {
            int rr = r0 + r; rr = (rr <= Bm1) ? rr : Bm1;   // clamp (no-op when B%64==0)
            const float* gp = src + (size_t)rr * stride + (cb + col);
            __builtin_amdgcn_global_load_lds((gas_fptr)gp, (las_fptr)(lb + t * 64), 4, 0, 0);
            // e += 64  ->  r += 2, col += 10, wrap at 27
            col += 64 - 2 * CCH;
            int w = (col >= CCH) ? 1 : 0;
            r += 2 + w;
            col -= w ? CCH : 0;
        }
    };

    float nsc[STATE];
#pragma unroll
    for (int d = 0; d < STATE; ++d) nsc[d] = 0.0f;
    float ir = 0.0f;

    // ---- 2-deep pipelined chunk loop: counted vmcnt, never drain mid-loop ----
    issue(0);
    issue(1);
#pragma unroll
    for (int c = 0; c < NCH; ++c) {
        if (c < NCH - 1) asm volatile("s_waitcnt vmcnt(27)" ::: "memory");  // chunk c landed
        else             asm volatile("s_waitcnt vmcnt(0)"  ::: "memory");
        const float* lb = &buf[c & 1][lane * CCH];   // stride 27 (odd) -> conflict-free
        if (c < NAF) {
            // scatter-add, all indices compile-time after unroll
#pragma unroll
            for (int j0 = 0; j0 < CCH; ++j0)
                nsc[DST.v[c * CCH + j0]] += lb[j0];
        } else {
            // demand chunk: immediate reward
#pragma unroll
            for (int j0 = 0; j0 < CCH; ++j0)
                ir += fminf(nsc[(c - NAF) * CCH + j0], lb[j0]);
        }
        // WAR fence: chunk c's ds_reads must be retired into VGPRs before we
        // issue chunk c+2's global_load_lds into the SAME buffer (buf[c&1]).
        // Without this, load-return data can land in LDS before the LDS unit
        // services the pending reads (the R1 correctness failure).
        asm volatile("s_waitcnt lgkmcnt(0)" ::: "memory");
        if (c + 2 < NCH) issue(c + 2);
    }

    // ---- coalesced nsc output: LDS round-trip, 3 rounds of 27 cols ----
#pragma unroll
    for (int rc = 0; rc < 3; ++rc) {
        float* lb = &buf[rc & 1][0];
#pragma unroll
        for (int j0 = 0; j0 < CCH; ++j0)
            lb[lane * CCH + j0] = nsc[rc * CCH + j0];
        int r = lr0, col = lc0;
#pragma unroll
        for (int t = 0; t < CCH; ++t) {
            int rr = r0 + r;
            if (rr < B)
                out[3 * (size_t)B + (size_t)rr * STATE + (rc * CCH + col)] = lb[t * 64 + lane];
            col += 64 - 2 * CCH;
            int w = (col >= CCH) ? 1 : 0;
            r += 2 + w;
            col -= w ? CCH : 0;
        }
    }

    // ---- MLP (per-thread, weights via uniform/scalar loads) ----
    float x1[H1];
#pragma unroll
    for (int j = 0; j < H1; ++j) x1[j] = 0.0f;
#pragma unroll
    for (int d = 0; d < STATE; ++d) {
        float v = nsc[d];
#pragma unroll
        for (int j = 0; j < H1; ++j) x1[j] = fmaf(v, W1[d * H1 + j], x1[j]);
    }
#pragma unroll
    for (int j = 0; j < H1; ++j) x1[j] = fmaxf(x1[j], 0.0f);

    float x2[H2];
#pragma unroll
    for (int j = 0; j < H2; ++j) x2[j] = 0.0f;
#pragma unroll
    for (int k = 0; k < H1; ++k) {
        float v = x1[k];
#pragma unroll
        for (int j = 0; j < H2; ++j) x2[j] = fmaf(v, W2[k * H2 + j], x2[j]);
    }
#pragma unroll
    for (int j = 0; j < H2; ++j) x2[j] = fmaxf(x2[j], 0.0f);

    float nr = b3[0];
#pragma unroll
    for (int k = 0; k < H2; ++k) nr = fmaf(x2[k], W3[k], nr);

    // ---- scalar outputs (coalesced: b == r0 + lane) ----
    int b = r0 + lane;
    if (b < B) {
        out[b] = ir + nr;            // symbolic_val
        out[(size_t)B + b] = ir;     // immediate_reward
        out[2 * (size_t)B + b] = nr; // next_return
    }
}

extern "C" void kernel_launch(void* const* d_in, const int* in_sizes, int n_in,
                              void* d_out, int out_size, void* d_ws, size_t ws_size,
                              hipStream_t stream) {
    const float* obs = (const float*)d_in[0];
    const float* ac  = (const float*)d_in[1];
    const float* W1  = (const float*)d_in[2];
    const float* W2  = (const float*)d_in[3];
    const float* W3  = (const float*)d_in[4];
    const float* b3  = (const float*)d_in[5];
    float* out = (float*)d_out;

    int B = in_sizes[0] / (3 * STATE);
    int block = ROWS;
    int grid = (B + ROWS - 1) / ROWS;
    hipLaunchKernelGGL(grid_vpn_kernel, dim3(grid), dim3(block), 0, stream,
                       obs, ac, W1, W2, W3, b3, out, B);
}

// Round 3
// 428.460 us; speedup vs baseline: 1.1561x; 1.1561x over previous
//
#include <hip/hip_runtime.h>

#define SIDE 9
#define STATE 81
#define NA 5
#define NJ (STATE * NA)   // 405
#define H1 32
#define H2 32

#define CCH 27            // chunk columns (405 = 15*27, 81 = 3*27)
#define BROWS 256         // rows per 256-thread block (4 waves)
#define NAF 15            // af chunks
#define NCH 18            // 15 af + 3 demand
#define OBS_STRIDE (3 * STATE)

// Compile-time inflow destination table: j = s*NA + a  ->  dest state.
struct DstTab { int v[NJ]; };
constexpr DstTab make_dst() {
    DstTab t{};
    const int dr[NA] = {0, -1, 1, 0, 0};
    const int dc[NA] = {0, 0, 0, -1, 1};
    for (int s = 0; s < STATE; ++s) {
        int r = s / SIDE, c = s % SIDE;
        for (int a = 0; a < NA; ++a) {
            int nr = r + dr[a], nc = c + dc[a];
            int d = (nr >= 0 && nr < SIDE && nc >= 0 && nc < SIDE) ? nr * SIDE + nc : s;
            t.v[s * NA + a] = d;
        }
    }
    return t;
}
constexpr DstTab DST = make_dst();

__global__ __launch_bounds__(256, 3) void grid_vpn_kernel(
    const float* __restrict__ obs,        // (B, 243)
    const float* __restrict__ af,         // (B, 405)
    const float* __restrict__ W1,         // (81, 32)
    const float* __restrict__ W2,         // (32, 32)
    const float* __restrict__ W3,         // (32, 1)
    const float* __restrict__ b3,         // (1,)
    float* __restrict__ out,              // [sym(B) | ir(B) | nr(B) | nsc(B*81)]
    int B)
{
    // Staging tile: 256 rows x 27 cols, flat e = r*27+c. 27648 B.
    // Reused for the output rounds (needs 64*81*4 = 20736 B).
    __shared__ float lb[BROWS * CCH];

    const int tid = (int)threadIdx.x;
    const int r0  = (int)blockIdx.x * BROWS;
    const int Bm1 = B - 1;

    // e = t*256 + tid -> (r = e/27, col = e%27); start point for t=0.
    const int sr_r0 = tid / CCH;
    const int sr_c0 = tid - sr_r0 * CCH;

    float nsc[STATE];
#pragma unroll
    for (int d = 0; d < STATE; ++d) nsc[d] = 0.0f;
    float ir = 0.0f;

    float stg[CCH];

    // Coalesced register-staged load of chunk c (27 elems/thread, e = t*256+tid).
    auto loadRegs = [&](int c, float (&s)[CCH]) {
        const float* src = (c < NAF) ? af : obs;
        const int stride = (c < NAF) ? NJ : OBS_STRIDE;
        const int cb     = (c < NAF) ? c * CCH : 2 * STATE + (c - NAF) * CCH;
        int r = sr_r0, col = sr_c0;
#pragma unroll
        for (int t = 0; t < CCH; ++t) {
            int rr = r0 + r; rr = (rr <= Bm1) ? rr : Bm1;  // no-op when B%256==0
            s[t] = src[(size_t)rr * stride + (cb + col)];
            // e += 256  ->  r += 9, col += 13, wrap at 27
            col += 256 - 9 * CCH;
            int w = (col >= CCH) ? 1 : 0;
            r += 9 + w;
            col -= w ? CCH : 0;
        }
    };

    // ---- pipelined chunk loop: reg-staged, raw barriers, no vmcnt drains ----
    loadRegs(0, stg);
#pragma unroll
    for (int c = 0; c < NCH; ++c) {
        // ds_write chunk c (compiler inserts precise vmcnt waits on the reg deps)
#pragma unroll
        for (int t = 0; t < CCH; ++t) lb[t * BROWS + tid] = stg[t];
        // issue next chunk's global loads NOW; they stay in flight across the
        // barriers (raw s_barrier has no implicit vmcnt drain) and land under
        // the consume phase below (T14 issue-early / write-late).
        if (c + 1 < NCH) loadRegs(c + 1, stg);
        asm volatile("s_waitcnt lgkmcnt(0)" ::: "memory");  // my ds_writes visible
        __builtin_amdgcn_s_barrier();
        // consume: thread owns row tid; LDS stride 27 (odd) -> conflict-free
        if (c < NAF) {
#pragma unroll
            for (int j = 0; j < CCH; ++j)
                nsc[DST.v[c * CCH + j]] += lb[tid * CCH + j];
        } else {
#pragma unroll
            for (int j = 0; j < CCH; ++j)
                ir += fminf(nsc[(c - NAF) * CCH + j], lb[tid * CCH + j]);
        }
        asm volatile("s_waitcnt lgkmcnt(0)" ::: "memory");  // my ds_reads retired (WAR)
        __builtin_amdgcn_s_barrier();
    }

    // ---- nsc output: flat full-line stores via LDS, 4 rounds of 64 rows ----
    // Block region out[3B + r0*81 ..] is contiguous: 20736 floats, 1024-B aligned.
    {
        const int wv = tid >> 6;
        const int ln = tid & 63;
        float* outns = out + 3 * (size_t)B + (size_t)r0 * STATE;
#pragma unroll
        for (int g = 0; g < 4; ++g) {
            if (wv == g) {
#pragma unroll
                for (int j = 0; j < STATE; ++j) lb[ln * STATE + j] = nsc[j];  // stride 81: 2-way, free
            }
            asm volatile("s_waitcnt lgkmcnt(0)" ::: "memory");
            __builtin_amdgcn_s_barrier();
            // 64*81 = 5184 floats = 20*256 + 64; every store full-line aligned
#pragma unroll
            for (int t = 0; t < 20; ++t)
                outns[g * 5184 + t * 256 + tid] = lb[t * 256 + tid];
            if (tid < 64) outns[g * 5184 + 5120 + tid] = lb[5120 + tid];
            asm volatile("s_waitcnt lgkmcnt(0)" ::: "memory");
            __builtin_amdgcn_s_barrier();
        }
    }

    // ---- MLP (per-thread, weights via scalar loads) ----
    float x1[H1];
#pragma unroll
    for (int j = 0; j < H1; ++j) x1[j] = 0.0f;
#pragma unroll
    for (int d = 0; d < STATE; ++d) {
        float v = nsc[d];
#pragma unroll
        for (int j = 0; j < H1; ++j) x1[j] = fmaf(v, W1[d * H1 + j], x1[j]);
    }
#pragma unroll
    for (int j = 0; j < H1; ++j) x1[j] = fmaxf(x1[j], 0.0f);

    float x2[H2];
#pragma unroll
    for (int j = 0; j < H2; ++j) x2[j] = 0.0f;
#pragma unroll
    for (int k = 0; k < H1; ++k) {
        float v = x1[k];
#pragma unroll
        for (int j = 0; j < H2; ++j) x2[j] = fmaf(v, W2[k * H2 + j], x2[j]);
    }
#pragma unroll
    for (int j = 0; j < H2; ++j) x2[j] = fmaxf(x2[j], 0.0f);

    float nr = b3[0];
#pragma unroll
    for (int k = 0; k < H2; ++k) nr = fmaf(x2[k], W3[k], nr);

    // ---- scalar outputs (coalesced full lines: b = r0 + tid) ----
    int b = r0 + tid;
    if (b < B) {
        out[b] = ir + nr;            // symbolic_val
        out[(size_t)B + b] = ir;     // immediate_reward
        out[2 * (size_t)B + b] = nr; // next_return
    }
}

extern "C" void kernel_launch(void* const* d_in, const int* in_sizes, int n_in,
                              void* d_out, int out_size, void* d_ws, size_t ws_size,
                              hipStream_t stream) {
    const float* obs = (const float*)d_in[0];
    const float* ac  = (const float*)d_in[1];
    const float* W1  = (const float*)d_in[2];
    const float* W2  = (const float*)d_in[3];
    const float* W3  = (const float*)d_in[4];
    const float* b3  = (const float*)d_in[5];
    float* out = (float*)d_out;

    int B = in_sizes[0] / (3 * STATE);
    int block = BROWS;
    int grid = (B + BROWS - 1) / BROWS;
    hipLaunchKernelGGL(grid_vpn_kernel, dim3(grid), dim3(block), 0, stream,
                       obs, ac, W1, W2, W3, b3, out, B);
}

// Round 4
// 398.582 us; speedup vs baseline: 1.2428x; 1.0750x over previous
//
#include <hip/hip_runtime.h>

#define SIDE 9
#define STATE 81
#define NA 5
#define NJ (STATE * NA)   // 405
#define H1 32
#define H2 32

#define CCH 27            // chunk columns (405 = 15*27, 81 = 3*27)
#define BROWS 256         // rows per 256-thread block (4 waves)
#define NAF 15            // af chunks
#define NCH 18            // 15 af + 3 demand
#define OBS_STRIDE (3 * STATE)

// Compile-time inflow destination table: j = s*NA + a  ->  dest state.
struct DstTab { int v[NJ]; };
constexpr DstTab make_dst() {
    DstTab t{};
    const int dr[NA] = {0, -1, 1, 0, 0};
    const int dc[NA] = {0, 0, 0, -1, 1};
    for (int s = 0; s < STATE; ++s) {
        int r = s / SIDE, c = s % SIDE;
        for (int a = 0; a < NA; ++a) {
            int nr = r + dr[a], nc = c + dc[a];
            int d = (nr >= 0 && nr < SIDE && nc >= 0 && nc < SIDE) ? nr * SIDE + nc : s;
            t.v[s * NA + a] = d;
        }
    }
    return t;
}
constexpr DstTab DST = make_dst();

// waves_per_eu(2,2): pin the register allocator's occupancy target.
// Live set through the chunk loop is nsc[81]+stg[27]+addr ~ 120 VGPRs; the
// default heuristic targeted 6 waves/EU (VGPR cap 84) and spilled ~35 regs
// to scratch -> scatter-add became L2-latency scratch RMW (the R3 limiter).
// Grid is 512 blocks = 2 blocks/CU = 2 waves/EU, so max=2 costs no occupancy.
__global__ __launch_bounds__(256) __attribute__((amdgpu_waves_per_eu(2, 2)))
void grid_vpn_kernel(
    const float* __restrict__ obs,        // (B, 243)
    const float* __restrict__ af,         // (B, 405)
    const float* __restrict__ W1,         // (81, 32)
    const float* __restrict__ W2,         // (32, 32)
    const float* __restrict__ W3,         // (32, 1)
    const float* __restrict__ b3,         // (1,)
    float* __restrict__ out,              // [sym(B) | ir(B) | nr(B) | nsc(B*81)]
    int B)
{
    // Staging tile: 256 rows x 27 cols, flat e = r*27+c. 27648 B.
    // Reused for the output rounds (needs 64*81*4 = 20736 B).
    __shared__ float lb[BROWS * CCH];

    const int tid = (int)threadIdx.x;
    const int r0  = (int)blockIdx.x * BROWS;
    const int Bm1 = B - 1;

    // e = t*256 + tid -> (r = e/27, col = e%27); start point for t=0.
    const int sr_r0 = tid / CCH;
    const int sr_c0 = tid - sr_r0 * CCH;

    float nsc[STATE];
#pragma unroll
    for (int d = 0; d < STATE; ++d) nsc[d] = 0.0f;
    float ir = 0.0f;

    float stg[CCH];

    // Coalesced register-staged load of chunk c (27 elems/thread, e = t*256+tid).
    auto loadRegs = [&](int c, float (&s)[CCH]) {
        const float* src = (c < NAF) ? af : obs;
        const int stride = (c < NAF) ? NJ : OBS_STRIDE;
        const int cb     = (c < NAF) ? c * CCH : 2 * STATE + (c - NAF) * CCH;
        int r = sr_r0, col = sr_c0;
#pragma unroll
        for (int t = 0; t < CCH; ++t) {
            int rr = r0 + r; rr = (rr <= Bm1) ? rr : Bm1;  // no-op when B%256==0
            s[t] = src[(size_t)rr * stride + (cb + col)];
            // e += 256  ->  r += 9, col += 13, wrap at 27
            col += 256 - 9 * CCH;
            int w = (col >= CCH) ? 1 : 0;
            r += 9 + w;
            col -= w ? CCH : 0;
        }
    };

    // ---- pipelined chunk loop: reg-staged, raw barriers, no vmcnt drains ----
    loadRegs(0, stg);
#pragma unroll
    for (int c = 0; c < NCH; ++c) {
        // ds_write chunk c (compiler inserts precise vmcnt waits on the reg deps)
#pragma unroll
        for (int t = 0; t < CCH; ++t) lb[t * BROWS + tid] = stg[t];
        // issue next chunk's global loads NOW; they stay in flight across the
        // barriers (raw s_barrier has no implicit vmcnt drain) and land under
        // the consume phase below (T14 issue-early / write-late).
        if (c + 1 < NCH) loadRegs(c + 1, stg);
        asm volatile("s_waitcnt lgkmcnt(0)" ::: "memory");  // my ds_writes visible
        __builtin_amdgcn_s_barrier();
        // consume: thread owns row tid; LDS stride 27 (odd) -> conflict-free
        if (c < NAF) {
#pragma unroll
            for (int j = 0; j < CCH; ++j)
                nsc[DST.v[c * CCH + j]] += lb[tid * CCH + j];
        } else {
#pragma unroll
            for (int j = 0; j < CCH; ++j)
                ir += fminf(nsc[(c - NAF) * CCH + j], lb[tid * CCH + j]);
        }
        asm volatile("s_waitcnt lgkmcnt(0)" ::: "memory");  // my ds_reads retired (WAR)
        __builtin_amdgcn_s_barrier();
    }

    // ---- nsc output: flat full-line stores via LDS, 4 rounds of 64 rows ----
    // Block region out[3B + r0*81 ..] is contiguous: 20736 floats, 1024-B aligned.
    {
        const int wv = tid >> 6;
        const int ln = tid & 63;
        float* outns = out + 3 * (size_t)B + (size_t)r0 * STATE;
#pragma unroll
        for (int g = 0; g < 4; ++g) {
            if (wv == g) {
#pragma unroll
                for (int j = 0; j < STATE; ++j) lb[ln * STATE + j] = nsc[j];  // stride 81: 2-way, free
            }
            asm volatile("s_waitcnt lgkmcnt(0)" ::: "memory");
            __builtin_amdgcn_s_barrier();
            // 64*81 = 5184 floats = 20*256 + 64; every store full-line aligned
#pragma unroll
            for (int t = 0; t < 20; ++t)
                outns[g * 5184 + t * 256 + tid] = lb[t * 256 + tid];
            if (tid < 64) outns[g * 5184 + 5120 + tid] = lb[5120 + tid];
            asm volatile("s_waitcnt lgkmcnt(0)" ::: "memory");
            __builtin_amdgcn_s_barrier();
        }
    }

    // ---- MLP (per-thread, weights via scalar loads) ----
    float x1[H1];
#pragma unroll
    for (int j = 0; j < H1; ++j) x1[j] = 0.0f;
#pragma unroll
    for (int d = 0; d < STATE; ++d) {
        float v = nsc[d];
#pragma unroll
        for (int j = 0; j < H1; ++j) x1[j] = fmaf(v, W1[d * H1 + j], x1[j]);
    }
#pragma unroll
    for (int j = 0; j < H1; ++j) x1[j] = fmaxf(x1[j], 0.0f);

    float x2[H2];
#pragma unroll
    for (int j = 0; j < H2; ++j) x2[j] = 0.0f;
#pragma unroll
    for (int k = 0; k < H1; ++k) {
        float v = x1[k];
#pragma unroll
        for (int j = 0; j < H2; ++j) x2[j] = fmaf(v, W2[k * H2 + j], x2[j]);
    }
#pragma unroll
    for (int j = 0; j < H2; ++j) x2[j] = fmaxf(x2[j], 0.0f);

    float nr = b3[0];
#pragma unroll
    for (int k = 0; k < H2; ++k) nr = fmaf(x2[k], W3[k], nr);

    // ---- scalar outputs (coalesced full lines: b = r0 + tid) ----
    int b = r0 + tid;
    if (b < B) {
        out[b] = ir + nr;            // symbolic_val
        out[(size_t)B + b] = ir;     // immediate_reward
        out[2 * (size_t)B + b] = nr; // next_return
    }
}

extern "C" void kernel_launch(void* const* d_in, const int* in_sizes, int n_in,
                              void* d_out, int out_size, void* d_ws, size_t ws_size,
                              hipStream_t stream) {
    const float* obs = (const float*)d_in[0];
    const float* ac  = (const float*)d_in[1];
    const float* W1  = (const float*)d_in[2];
    const float* W2  = (const float*)d_in[3];
    const float* W3  = (const float*)d_in[4];
    const float* b3  = (const float*)d_in[5];
    float* out = (float*)d_out;

    int B = in_sizes[0] / (3 * STATE);
    int block = BROWS;
    int grid = (B + BROWS - 1) / BROWS;
    hipLaunchKernelGGL(grid_vpn_kernel, dim3(grid), dim3(block), 0, stream,
                       obs, ac, W1, W2, W3, b3, out, B);
}